// Round 2
// baseline (12018.123 us; speedup 1.0000x reference)
//
#include <hip/hip_runtime.h>
#include <math.h>

#define B_ 8
#define S_ 256
#define H_ 768
#define NL_ 12
#define NH_ 12
#define DH_ 64
#define FF_ 3072
#define NT_ 9
#define TLEN_ 254
#define NEG_ -10000.0f
#define TOK_ (B_ * S_)   // 2048

// ---------------------------------------------------------------------------
// Block-wide sum+sumsq reduction (256 threads)
// ---------------------------------------------------------------------------
__device__ __forceinline__ void block_reduce2(float& sum, float& ssq) {
    #pragma unroll
    for (int off = 32; off; off >>= 1) {
        sum += __shfl_down(sum, off);
        ssq += __shfl_down(ssq, off);
    }
    __shared__ float rs[4], rq[4];
    const int w = threadIdx.x >> 6;
    if ((threadIdx.x & 63) == 0) { rs[w] = sum; rq[w] = ssq; }
    __syncthreads();
    sum = rs[0] + rs[1] + rs[2] + rs[3];
    ssq = rq[0] + rq[1] + rq[2] + rq[3];
}

// ---------------------------------------------------------------------------
// Embedding gather + LayerNorm  (one block per token, 256 threads, 3 elem/thr)
// ---------------------------------------------------------------------------
__global__ __launch_bounds__(256) void embed_ln_kernel(
        const int* __restrict__ sent, const float* __restrict__ we,
        const float* __restrict__ pe, const float* __restrict__ te,
        const float* __restrict__ g, const float* __restrict__ bb,
        float* __restrict__ out) {
    const int row = blockIdx.x;          // b*256 + s
    const int s   = row & (S_ - 1);
    const int tid = threadIdx.x;
    const int id  = sent[row];
    float v[3];
    #pragma unroll
    for (int u = 0; u < 3; ++u) {
        const int i = tid + u * 256;
        v[u] = we[(long)id * H_ + i] + pe[s * H_ + i] + te[i];
    }
    float sum = v[0] + v[1] + v[2];
    float ssq = v[0]*v[0] + v[1]*v[1] + v[2]*v[2];
    block_reduce2(sum, ssq);
    const float mean = sum * (1.0f / H_);
    const float var  = ssq * (1.0f / H_) - mean * mean;
    const float inv  = 1.0f / sqrtf(var + 1e-12f);
    #pragma unroll
    for (int u = 0; u < 3; ++u) {
        const int i = tid + u * 256;
        out[row * H_ + i] = (v[u] - mean) * inv * g[i] + bb[i];
    }
}

// ---------------------------------------------------------------------------
// Residual add + LayerNorm: out = LN(x + y) * s + b   (in-place into x OK)
// ---------------------------------------------------------------------------
__global__ __launch_bounds__(256) void resid_ln_kernel(
        const float* __restrict__ x, const float* __restrict__ y,
        const float* __restrict__ g, const float* __restrict__ bb,
        float* __restrict__ out) {
    const int row = blockIdx.x;
    const int tid = threadIdx.x;
    float v[3];
    #pragma unroll
    for (int u = 0; u < 3; ++u) {
        const int i = tid + u * 256;
        v[u] = x[row * H_ + i] + y[row * H_ + i];
    }
    float sum = v[0] + v[1] + v[2];
    float ssq = v[0]*v[0] + v[1]*v[1] + v[2]*v[2];
    block_reduce2(sum, ssq);
    const float mean = sum * (1.0f / H_);
    const float var  = ssq * (1.0f / H_) - mean * mean;
    const float inv  = 1.0f / sqrtf(var + 1e-12f);
    #pragma unroll
    for (int u = 0; u < 3; ++u) {
        const int i = tid + u * 256;
        out[row * H_ + i] = (v[u] - mean) * inv * g[i] + bb[i];
    }
}

// ---------------------------------------------------------------------------
// Tiled fp32 GEMM: C[M,N] = A[M,K] @ B[K,N] + bias[N]; EPI==1 -> exact GELU
// 128x64 tile, BK=16, 256 threads, 8x4 per thread. Dims assumed % tile.
// Per K-step per thread: 3 ds_read_b128 per 32 FMAs -> FMA-pipe-bound.
// ---------------------------------------------------------------------------
template <int EPI>
__global__ __launch_bounds__(256) void gemm_kernel(
        const float* __restrict__ A, const float* __restrict__ B,
        const float* __restrict__ bias, float* __restrict__ C,
        int M, int N, int K) {
    __shared__ float As[16][136];   // [k][m], padded
    __shared__ float Bs[16][72];    // [k][n], padded
    const int tid  = threadIdx.x;
    const int row0 = blockIdx.y * 128;
    const int col0 = blockIdx.x * 64;
    const int tm = (tid >> 4) * 8;        // 0..120
    const int tn = (tid & 15) * 4;        // 0..60
    // A-staging: 128x16 floats, 2 float4 per thread
    const int a_row = tid >> 1;           // 0..127
    const int a_k   = (tid & 1) * 8;      // 0 or 8
    // B-staging: 16x64 floats, 1 float4 per thread
    const int b_k   = tid >> 4;           // 0..15
    const int b_c   = (tid & 15) * 4;     // 0..60

    float acc[8][4] = {};
    const float* Aptr = A + (long)(row0 + a_row) * K + a_k;
    const float* Bptr = B + (long)b_k * N + col0 + b_c;

    for (int k0 = 0; k0 < K; k0 += 16) {
        const float4 av0 = *(const float4*)(Aptr + k0);
        const float4 av1 = *(const float4*)(Aptr + k0 + 4);
        const float4 bv  = *(const float4*)(Bptr + (long)k0 * N);
        As[a_k + 0][a_row] = av0.x;
        As[a_k + 1][a_row] = av0.y;
        As[a_k + 2][a_row] = av0.z;
        As[a_k + 3][a_row] = av0.w;
        As[a_k + 4][a_row] = av1.x;
        As[a_k + 5][a_row] = av1.y;
        As[a_k + 6][a_row] = av1.z;
        As[a_k + 7][a_row] = av1.w;
        *(float4*)&Bs[b_k][b_c] = bv;
        __syncthreads();
        #pragma unroll
        for (int kk = 0; kk < 16; ++kk) {
            const float4 a0 = *(const float4*)&As[kk][tm];
            const float4 a1 = *(const float4*)&As[kk][tm + 4];
            const float4 b4 = *(const float4*)&Bs[kk][tn];
            const float ar[8] = {a0.x, a0.y, a0.z, a0.w, a1.x, a1.y, a1.z, a1.w};
            const float br[4] = {b4.x, b4.y, b4.z, b4.w};
            #pragma unroll
            for (int i = 0; i < 8; ++i)
                #pragma unroll
                for (int j = 0; j < 4; ++j)
                    acc[i][j] += ar[i] * br[j];
        }
        __syncthreads();
    }

    const float4 bv4 = *(const float4*)&bias[col0 + tn];
    const float bvals[4] = {bv4.x, bv4.y, bv4.z, bv4.w};
    #pragma unroll
    for (int i = 0; i < 8; ++i) {
        float o[4];
        #pragma unroll
        for (int j = 0; j < 4; ++j) {
            float z = acc[i][j] + bvals[j];
            if (EPI == 1) z = 0.5f * z * (1.0f + erff(z * 0.70710678118654752f));
            o[j] = z;
        }
        *(float4*)&C[(long)(row0 + tm + i) * N + col0 + tn] = *(float4*)o;
    }
}

// ---------------------------------------------------------------------------
// Fused attention: one block per (b, head); thread = one query row.
// Online softmax over 4 key tiles of 64, chunks of 16.
// O may alias Q (each thread reads its own row fully before writing it).
// ---------------------------------------------------------------------------
__global__ __launch_bounds__(256) void attn_kernel(
        const float* __restrict__ Q, const float* __restrict__ K,
        const float* __restrict__ V, float* __restrict__ O) {
    const int bh  = blockIdx.x;
    const int b   = bh / NH_;
    const int h   = bh % NH_;
    const int tid = threadIdx.x;                 // query index 0..255
    __shared__ float Ks[64][68];
    __shared__ float Vs[64][68];
    const long base = (long)(b * S_) * H_ + h * DH_;

    float qr[64];
    #pragma unroll
    for (int d4 = 0; d4 < 16; ++d4) {
        const float4 t = *(const float4*)&Q[base + (long)tid * H_ + d4 * 4];
        qr[d4*4+0] = t.x * 0.125f; qr[d4*4+1] = t.y * 0.125f;
        qr[d4*4+2] = t.z * 0.125f; qr[d4*4+3] = t.w * 0.125f;
    }
    float acc[64] = {0.0f};
    float m_run = -1e30f, l_run = 0.0f;

    for (int kt = 0; kt < 4; ++kt) {
        __syncthreads();
        #pragma unroll
        for (int u = 0; u < 4; ++u) {
            const int idx = tid + u * 256;
            const int r = idx >> 4, c = (idx & 15) * 4;
            *(float4*)&Ks[r][c] = *(const float4*)&K[base + (long)(kt*64 + r) * H_ + c];
            *(float4*)&Vs[r][c] = *(const float4*)&V[base + (long)(kt*64 + r) * H_ + c];
        }
        __syncthreads();
        for (int ch = 0; ch < 4; ++ch) {
            float sreg[16];
            float mx = -1e30f;
            #pragma unroll
            for (int jj = 0; jj < 16; ++jj) {
                const int j = ch * 16 + jj;
                float a = 0.0f;
                #pragma unroll
                for (int d4 = 0; d4 < 16; ++d4) {
                    const float4 kv = *(const float4*)&Ks[j][d4 * 4];
                    a += qr[d4*4+0]*kv.x + qr[d4*4+1]*kv.y
                       + qr[d4*4+2]*kv.z + qr[d4*4+3]*kv.w;
                }
                sreg[jj] = a;
                mx = fmaxf(mx, a);
            }
            const float m_new = fmaxf(m_run, mx);
            const float corr  = __expf(m_run - m_new);
            l_run *= corr;
            #pragma unroll
            for (int d = 0; d < 64; ++d) acc[d] *= corr;
            #pragma unroll
            for (int jj = 0; jj < 16; ++jj) {
                const float p = __expf(sreg[jj] - m_new);
                l_run += p;
                const int j = ch * 16 + jj;
                #pragma unroll
                for (int d4 = 0; d4 < 16; ++d4) {
                    const float4 vv = *(const float4*)&Vs[j][d4 * 4];
                    acc[d4*4+0] += p * vv.x; acc[d4*4+1] += p * vv.y;
                    acc[d4*4+2] += p * vv.z; acc[d4*4+3] += p * vv.w;
                }
            }
            m_run = m_new;
        }
    }
    __syncthreads();
    const float inv = 1.0f / l_run;
    #pragma unroll
    for (int d4 = 0; d4 < 16; ++d4) {
        float o[4];
        o[0] = acc[d4*4+0] * inv; o[1] = acc[d4*4+1] * inv;
        o[2] = acc[d4*4+2] * inv; o[3] = acc[d4*4+3] * inv;
        *(float4*)&O[base + (long)tid * H_ + d4 * 4] = *(float4*)o;
    }
}

// ---------------------------------------------------------------------------
// Final FC: feats[row, 0..8] = x[row,:] @ fc_w + fc_b  (one wave per row)
// ---------------------------------------------------------------------------
__global__ __launch_bounds__(64) void fc_kernel(
        const float* __restrict__ x, const float* __restrict__ w,
        const float* __restrict__ wb, float* __restrict__ feats) {
    const int row  = blockIdx.x;
    const int lane = threadIdx.x;
    float acc[NT_] = {};
    for (int i = lane; i < H_; i += 64) {
        const float xv = x[(long)row * H_ + i];
        #pragma unroll
        for (int t = 0; t < NT_; ++t) acc[t] += xv * w[i * NT_ + t];
    }
    #pragma unroll
    for (int t = 0; t < NT_; ++t) {
        #pragma unroll
        for (int off = 32; off; off >>= 1) acc[t] += __shfl_down(acc[t], off);
    }
    if (lane == 0) {
        #pragma unroll
        for (int t = 0; t < NT_; ++t) feats[row * NT_ + t] = acc[t] + wb[t];
    }
}

// ---------------------------------------------------------------------------
// Viterbi: single block. Forward 254 steps (72 active threads), then backtrack.
// out[0..7] = score; out[8 + b*254 + t] = path tag (as float).
// ---------------------------------------------------------------------------
__global__ __launch_bounds__(128) void viterbi_kernel(
        const float* __restrict__ feats, const float* __restrict__ trans,
        float* __restrict__ out, int* __restrict__ bps) {
    __shared__ float fv[B_][NT_];
    __shared__ float fvn[B_][NT_];
    __shared__ float tr[NT_ * NT_];
    const int tid = threadIdx.x;
    if (tid < NT_ * NT_) tr[tid] = trans[tid];
    if (tid < B_ * NT_) {
        const int b = tid / NT_, i = tid % NT_;
        fv[b][i] = (i == 7) ? 0.0f : NEG_;
    }
    __syncthreads();
    for (int t = 0; t < TLEN_; ++t) {
        if (tid < B_ * NT_) {
            const int b = tid / NT_, i = tid % NT_;
            float best = fv[b][0] + tr[i * NT_ + 0];
            int bj = 0;
            #pragma unroll
            for (int j = 1; j < NT_; ++j) {
                const float c = fv[b][j] + tr[i * NT_ + j];
                if (c > best) { best = c; bj = j; }
            }
            bps[(t * B_ + b) * NT_ + i] = bj;
            fvn[b][i] = best + feats[((b * S_) + 1 + t) * NT_ + i];
        }
        __syncthreads();
        if (tid < B_ * NT_) {
            const int b = tid / NT_, i = tid % NT_;
            fv[b][i] = fvn[b][i];
        }
        __syncthreads();
    }
    if (tid < B_) {
        const int b = tid;
        float best = fv[b][0] + tr[8 * NT_ + 0];
        int bi = 0;
        #pragma unroll
        for (int i = 1; i < NT_; ++i) {
            const float c = fv[b][i] + tr[8 * NT_ + i];
            if (c > best) { best = c; bi = i; }
        }
        out[b] = best;
        float* path = out + B_ + b * TLEN_;
        int tag = bi;
        path[TLEN_ - 1] = (float)tag;
        for (int t = TLEN_ - 2; t >= 0; --t) {
            tag = bps[((t + 1) * B_ + b) * NT_ + tag];
            path[t] = (float)tag;
        }
    }
}

// ---------------------------------------------------------------------------
// Host orchestration
// ---------------------------------------------------------------------------
extern "C" void kernel_launch(void* const* d_in, const int* in_sizes, int n_in,
                              void* d_out, int out_size, void* d_ws, size_t ws_size,
                              hipStream_t stream) {
    const int*   sentences = (const int*)  d_in[0];
    // d_in[1] = targets_length (static 254)
    const float* word_emb  = (const float*)d_in[2];
    const float* pos_emb   = (const float*)d_in[3];
    const float* type_emb  = (const float*)d_in[4];
    const float* emb_ln_s  = (const float*)d_in[5];
    const float* emb_ln_b  = (const float*)d_in[6];
    const float* Wq = (const float*)d_in[7];
    const float* bq = (const float*)d_in[8];
    const float* Wk = (const float*)d_in[9];
    const float* bk = (const float*)d_in[10];
    const float* Wv = (const float*)d_in[11];
    const float* bv = (const float*)d_in[12];
    const float* Wo = (const float*)d_in[13];
    const float* bo = (const float*)d_in[14];
    const float* ln1_s = (const float*)d_in[15];
    const float* ln1_b = (const float*)d_in[16];
    const float* W1 = (const float*)d_in[17];
    const float* b1 = (const float*)d_in[18];
    const float* W2 = (const float*)d_in[19];
    const float* b2 = (const float*)d_in[20];
    const float* ln2_s = (const float*)d_in[21];
    const float* ln2_b = (const float*)d_in[22];
    const float* fc_w  = (const float*)d_in[23];
    const float* fc_b  = (const float*)d_in[24];
    const float* transitions = (const float*)d_in[25];

    float* wsf = (float*)d_ws;
    const long NTOKH = (long)TOK_ * H_;        // 1,572,864
    float* x    = wsf;
    float* q    = x + NTOKH;
    float* kbuf = q + NTOKH;                   // also GEMM output temp
    float* vbuf = kbuf + NTOKH;
    float* ffh  = vbuf + NTOKH;
    float* feats = ffh + (long)TOK_ * FF_;
    int*   bps  = (int*)(feats + (long)TOK_ * NT_);

    // Embedding + LN
    embed_ln_kernel<<<TOK_, 256, 0, stream>>>(sentences, word_emb, pos_emb,
                                              type_emb, emb_ln_s, emb_ln_b, x);

    const dim3 gH(H_ / 64, TOK_ / 128);    // 12 x 16
    const dim3 gF(FF_ / 64, TOK_ / 128);   // 48 x 16

    for (int l = 0; l < NL_; ++l) {
        const float* Wq_l = Wq + (long)l * H_ * H_;
        const float* Wk_l = Wk + (long)l * H_ * H_;
        const float* Wv_l = Wv + (long)l * H_ * H_;
        const float* Wo_l = Wo + (long)l * H_ * H_;
        const float* W1_l = W1 + (long)l * H_ * FF_;
        const float* W2_l = W2 + (long)l * FF_ * H_;

        gemm_kernel<0><<<gH, 256, 0, stream>>>(x, Wq_l, bq + l * H_, q,    TOK_, H_, H_);
        gemm_kernel<0><<<gH, 256, 0, stream>>>(x, Wk_l, bk + l * H_, kbuf, TOK_, H_, H_);
        gemm_kernel<0><<<gH, 256, 0, stream>>>(x, Wv_l, bv + l * H_, vbuf, TOK_, H_, H_);

        attn_kernel<<<B_ * NH_, 256, 0, stream>>>(q, kbuf, vbuf, q);  // ctx -> q

        gemm_kernel<0><<<gH, 256, 0, stream>>>(q, Wo_l, bo + l * H_, kbuf, TOK_, H_, H_);
        resid_ln_kernel<<<TOK_, 256, 0, stream>>>(x, kbuf, ln1_s + l * H_, ln1_b + l * H_, x);

        gemm_kernel<1><<<gF, 256, 0, stream>>>(x, W1_l, b1 + l * FF_, ffh, TOK_, FF_, H_);
        gemm_kernel<0><<<gH, 256, 0, stream>>>(ffh, W2_l, b2 + l * H_, kbuf, TOK_, H_, FF_);
        resid_ln_kernel<<<TOK_, 256, 0, stream>>>(x, kbuf, ln2_s + l * H_, ln2_b + l * H_, x);
    }

    fc_kernel<<<TOK_, 64, 0, stream>>>(x, fc_w, fc_b, feats);
    viterbi_kernel<<<1, 128, 0, stream>>>(feats, transitions, (float*)d_out, bps);
}

// Round 3
// 7098.480 us; speedup vs baseline: 1.6931x; 1.6931x over previous
//
#include <hip/hip_runtime.h>
#include <math.h>

#define B_ 8
#define S_ 256
#define H_ 768
#define NL_ 12
#define NH_ 12
#define DH_ 64
#define FF_ 3072
#define NT_ 9
#define TLEN_ 254
#define NEG_ -10000.0f
#define TOK_ (B_ * S_)   // 2048

typedef __bf16 bf16x8 __attribute__((ext_vector_type(8)));
typedef float  f32x4  __attribute__((ext_vector_type(4)));

// ---------------------------------------------------------------------------
// bf16 split helpers: f ≈ hi + lo with hi,lo bf16 (RNE). Error ~2^-17 rel.
// ---------------------------------------------------------------------------
__device__ __forceinline__ unsigned short bf16_rne(float f) {
    unsigned int u = __float_as_uint(f);
    unsigned int r = u + 0x7FFFu + ((u >> 16) & 1u);
    return (unsigned short)(r >> 16);
}
__device__ __forceinline__ void split_bf16(float f, unsigned short& h, unsigned short& l) {
    h = bf16_rne(f);
    const float hf = __uint_as_float((unsigned int)h << 16);
    l = bf16_rne(f - hf);
}

// ---------------------------------------------------------------------------
// Block-wide sum+sumsq reduction (256 threads)
// ---------------------------------------------------------------------------
__device__ __forceinline__ void block_reduce2(float& sum, float& ssq) {
    #pragma unroll
    for (int off = 32; off; off >>= 1) {
        sum += __shfl_down(sum, off);
        ssq += __shfl_down(ssq, off);
    }
    __shared__ float rs[4], rq[4];
    const int w = threadIdx.x >> 6;
    if ((threadIdx.x & 63) == 0) { rs[w] = sum; rq[w] = ssq; }
    __syncthreads();
    sum = rs[0] + rs[1] + rs[2] + rs[3];
    ssq = rq[0] + rq[1] + rq[2] + rq[3];
}

// ---------------------------------------------------------------------------
// Embedding gather + LayerNorm  (one block per token)
// ---------------------------------------------------------------------------
__global__ __launch_bounds__(256) void embed_ln_kernel(
        const int* __restrict__ sent, const float* __restrict__ we,
        const float* __restrict__ pe, const float* __restrict__ te,
        const float* __restrict__ g, const float* __restrict__ bb,
        float* __restrict__ out) {
    const int row = blockIdx.x;
    const int s   = row & (S_ - 1);
    const int tid = threadIdx.x;
    const int id  = sent[row];
    float v[3];
    #pragma unroll
    for (int u = 0; u < 3; ++u) {
        const int i = tid + u * 256;
        v[u] = we[(long)id * H_ + i] + pe[s * H_ + i] + te[i];
    }
    float sum = v[0] + v[1] + v[2];
    float ssq = v[0]*v[0] + v[1]*v[1] + v[2]*v[2];
    block_reduce2(sum, ssq);
    const float mean = sum * (1.0f / H_);
    const float var  = ssq * (1.0f / H_) - mean * mean;
    const float inv  = 1.0f / sqrtf(var + 1e-12f);
    #pragma unroll
    for (int u = 0; u < 3; ++u) {
        const int i = tid + u * 256;
        out[row * H_ + i] = (v[u] - mean) * inv * g[i] + bb[i];
    }
}

// ---------------------------------------------------------------------------
// Residual add + LayerNorm
// ---------------------------------------------------------------------------
__global__ __launch_bounds__(256) void resid_ln_kernel(
        const float* __restrict__ x, const float* __restrict__ y,
        const float* __restrict__ g, const float* __restrict__ bb,
        float* __restrict__ out) {
    const int row = blockIdx.x;
    const int tid = threadIdx.x;
    float v[3];
    #pragma unroll
    for (int u = 0; u < 3; ++u) {
        const int i = tid + u * 256;
        v[u] = x[row * H_ + i] + y[row * H_ + i];
    }
    float sum = v[0] + v[1] + v[2];
    float ssq = v[0]*v[0] + v[1]*v[1] + v[2]*v[2];
    block_reduce2(sum, ssq);
    const float mean = sum * (1.0f / H_);
    const float var  = ssq * (1.0f / H_) - mean * mean;
    const float inv  = 1.0f / sqrtf(var + 1e-12f);
    #pragma unroll
    for (int u = 0; u < 3; ++u) {
        const int i = tid + u * 256;
        out[row * H_ + i] = (v[u] - mean) * inv * g[i] + bb[i];
    }
}

// ---------------------------------------------------------------------------
// MFMA bf16 split-precision GEMM: C = A[M,K] @ B[K,N] + bias; EPI==1 -> GELU.
// acc += Ahi*Bhi + Ahi*Blo + Alo*Bhi  (fp32 MFMA accumulate, ~2^-17 rel err).
// Block 64x64, BK=32, 4 waves of 32x32 (2x2 frags of 16x16x32).
// LDS rows padded to 40 bf16 (80B) -> frag ds_read_b128 = 2-way banks (free).
// Conversion fp32->bf16 hi/lo fused into staging (same global bytes as fp32).
// ---------------------------------------------------------------------------
template <int EPI>
__global__ __launch_bounds__(256) void mfma_gemm_kernel(
        const float* __restrict__ A, const float* __restrict__ B,
        const float* __restrict__ bias, float* __restrict__ C,
        int M, int N, int K) {
    __shared__ unsigned short As_hi[64 * 40];
    __shared__ unsigned short As_lo[64 * 40];
    __shared__ unsigned short Bs_hi[64 * 40];
    __shared__ unsigned short Bs_lo[64 * 40];

    const int tid  = threadIdx.x;
    const int lane = tid & 63;
    const int wid  = tid >> 6;
    const int row0 = blockIdx.y * 64;
    const int col0 = blockIdx.x * 64;
    const int wm = (wid >> 1) * 32;      // wave row offset in block
    const int wn = (wid & 1) * 32;       // wave col offset in block
    const int lr = lane & 15;            // fragment row/col within 16
    const int lk = (lane >> 4) * 8;      // fragment k-offset (8 bf16)

    // A staging: row = tid>>2 (0..63), k-quad = tid&3 (+ second quad at +16)
    const int ar = tid >> 2, aq = tid & 3;
    // B staging: n = tid>>2 (0..63), k-quad = tid&3 (+ second quad at +16)
    const int bn = tid >> 2, bq = tid & 3;

    const float* Ap = A + (long)(row0 + ar) * K + aq * 4;
    const float* Bp = B + (long)(bq * 4) * N + col0 + bn;

    f32x4 acc[2][2];
    #pragma unroll
    for (int mi = 0; mi < 2; ++mi)
        #pragma unroll
        for (int nj = 0; nj < 2; ++nj)
            acc[mi][nj] = (f32x4)(0.0f);

    for (int k0 = 0; k0 < K; k0 += 32) {
        // ---- global loads (fp32) ----
        const float4 av0 = *(const float4*)(Ap + k0);
        const float4 av1 = *(const float4*)(Ap + k0 + 16);
        float bvf[8];
        #pragma unroll
        for (int i = 0; i < 4; ++i) bvf[i]     = Bp[(long)(k0 + i) * N];
        #pragma unroll
        for (int i = 0; i < 4; ++i) bvf[4 + i] = Bp[(long)(k0 + 16 + i) * N];

        // ---- convert to hi/lo bf16 ----
        const float afv[8] = {av0.x, av0.y, av0.z, av0.w, av1.x, av1.y, av1.z, av1.w};
        unsigned short ah8[8], al8[8], bh8[8], bl8[8];
        #pragma unroll
        for (int i = 0; i < 8; ++i) { split_bf16(afv[i], ah8[i], al8[i]); }
        #pragma unroll
        for (int i = 0; i < 8; ++i) { split_bf16(bvf[i], bh8[i], bl8[i]); }

        __syncthreads();   // previous iteration's reads complete

        *(ushort4*)&As_hi[ar * 40 + aq * 4]      = make_ushort4(ah8[0], ah8[1], ah8[2], ah8[3]);
        *(ushort4*)&As_hi[ar * 40 + aq * 4 + 16] = make_ushort4(ah8[4], ah8[5], ah8[6], ah8[7]);
        *(ushort4*)&As_lo[ar * 40 + aq * 4]      = make_ushort4(al8[0], al8[1], al8[2], al8[3]);
        *(ushort4*)&As_lo[ar * 40 + aq * 4 + 16] = make_ushort4(al8[4], al8[5], al8[6], al8[7]);
        *(ushort4*)&Bs_hi[bn * 40 + bq * 4]      = make_ushort4(bh8[0], bh8[1], bh8[2], bh8[3]);
        *(ushort4*)&Bs_hi[bn * 40 + bq * 4 + 16] = make_ushort4(bh8[4], bh8[5], bh8[6], bh8[7]);
        *(ushort4*)&Bs_lo[bn * 40 + bq * 4]      = make_ushort4(bl8[0], bl8[1], bl8[2], bl8[3]);
        *(ushort4*)&Bs_lo[bn * 40 + bq * 4 + 16] = make_ushort4(bl8[4], bl8[5], bl8[6], bl8[7]);

        __syncthreads();   // tile staged

        bf16x8 ah[2], al[2], bh[2], bl[2];
        #pragma unroll
        for (int mi = 0; mi < 2; ++mi) {
            ah[mi] = *(const bf16x8*)&As_hi[(wm + mi * 16 + lr) * 40 + lk];
            al[mi] = *(const bf16x8*)&As_lo[(wm + mi * 16 + lr) * 40 + lk];
        }
        #pragma unroll
        for (int nj = 0; nj < 2; ++nj) {
            bh[nj] = *(const bf16x8*)&Bs_hi[(wn + nj * 16 + lr) * 40 + lk];
            bl[nj] = *(const bf16x8*)&Bs_lo[(wn + nj * 16 + lr) * 40 + lk];
        }
        #pragma unroll
        for (int mi = 0; mi < 2; ++mi)
            #pragma unroll
            for (int nj = 0; nj < 2; ++nj) {
                acc[mi][nj] = __builtin_amdgcn_mfma_f32_16x16x32_bf16(ah[mi], bh[nj], acc[mi][nj], 0, 0, 0);
                acc[mi][nj] = __builtin_amdgcn_mfma_f32_16x16x32_bf16(ah[mi], bl[nj], acc[mi][nj], 0, 0, 0);
                acc[mi][nj] = __builtin_amdgcn_mfma_f32_16x16x32_bf16(al[mi], bh[nj], acc[mi][nj], 0, 0, 0);
            }
    }

    // ---- epilogue: C/D layout col=lane&15, row=(lane>>4)*4+reg (m89) ----
    #pragma unroll
    for (int nj = 0; nj < 2; ++nj) {
        const int col = col0 + wn + nj * 16 + lr;
        const float bval = bias[col];
        #pragma unroll
        for (int mi = 0; mi < 2; ++mi) {
            const int rowb = row0 + wm + mi * 16 + (lane >> 4) * 4;
            #pragma unroll
            for (int r = 0; r < 4; ++r) {
                float z = acc[mi][nj][r] + bval;
                if (EPI == 1) z = 0.5f * z * (1.0f + erff(z * 0.70710678118654752f));
                C[(long)(rowb + r) * N + col] = z;
            }
        }
    }
}

// ---------------------------------------------------------------------------
// Fused attention: one block per (b, head); thread = one query row.
// ---------------------------------------------------------------------------
__global__ __launch_bounds__(256) void attn_kernel(
        const float* __restrict__ Q, const float* __restrict__ K,
        const float* __restrict__ V, float* __restrict__ O) {
    const int bh  = blockIdx.x;
    const int b   = bh / NH_;
    const int h   = bh % NH_;
    const int tid = threadIdx.x;
    __shared__ float Ks[64][68];
    __shared__ float Vs[64][68];
    const long base = (long)(b * S_) * H_ + h * DH_;

    float qr[64];
    #pragma unroll
    for (int d4 = 0; d4 < 16; ++d4) {
        const float4 t = *(const float4*)&Q[base + (long)tid * H_ + d4 * 4];
        qr[d4*4+0] = t.x * 0.125f; qr[d4*4+1] = t.y * 0.125f;
        qr[d4*4+2] = t.z * 0.125f; qr[d4*4+3] = t.w * 0.125f;
    }
    float acc[64] = {0.0f};
    float m_run = -1e30f, l_run = 0.0f;

    for (int kt = 0; kt < 4; ++kt) {
        __syncthreads();
        #pragma unroll
        for (int u = 0; u < 4; ++u) {
            const int idx = tid + u * 256;
            const int r = idx >> 4, c = (idx & 15) * 4;
            *(float4*)&Ks[r][c] = *(const float4*)&K[base + (long)(kt*64 + r) * H_ + c];
            *(float4*)&Vs[r][c] = *(const float4*)&V[base + (long)(kt*64 + r) * H_ + c];
        }
        __syncthreads();
        for (int ch = 0; ch < 4; ++ch) {
            float sreg[16];
            float mx = -1e30f;
            #pragma unroll
            for (int jj = 0; jj < 16; ++jj) {
                const int j = ch * 16 + jj;
                float a = 0.0f;
                #pragma unroll
                for (int d4 = 0; d4 < 16; ++d4) {
                    const float4 kv = *(const float4*)&Ks[j][d4 * 4];
                    a += qr[d4*4+0]*kv.x + qr[d4*4+1]*kv.y
                       + qr[d4*4+2]*kv.z + qr[d4*4+3]*kv.w;
                }
                sreg[jj] = a;
                mx = fmaxf(mx, a);
            }
            const float m_new = fmaxf(m_run, mx);
            const float corr  = __expf(m_run - m_new);
            l_run *= corr;
            #pragma unroll
            for (int d = 0; d < 64; ++d) acc[d] *= corr;
            #pragma unroll
            for (int jj = 0; jj < 16; ++jj) {
                const float p = __expf(sreg[jj] - m_new);
                l_run += p;
                const int j = ch * 16 + jj;
                #pragma unroll
                for (int d4 = 0; d4 < 16; ++d4) {
                    const float4 vv = *(const float4*)&Vs[j][d4 * 4];
                    acc[d4*4+0] += p * vv.x; acc[d4*4+1] += p * vv.y;
                    acc[d4*4+2] += p * vv.z; acc[d4*4+3] += p * vv.w;
                }
            }
            m_run = m_new;
        }
    }
    __syncthreads();
    const float inv = 1.0f / l_run;
    #pragma unroll
    for (int d4 = 0; d4 < 16; ++d4) {
        float o[4];
        o[0] = acc[d4*4+0] * inv; o[1] = acc[d4*4+1] * inv;
        o[2] = acc[d4*4+2] * inv; o[3] = acc[d4*4+3] * inv;
        *(float4*)&O[base + (long)tid * H_ + d4 * 4] = *(float4*)o;
    }
}

// ---------------------------------------------------------------------------
// Final FC: feats[row, 0..8] = x[row,:] @ fc_w + fc_b  (one wave per row)
// ---------------------------------------------------------------------------
__global__ __launch_bounds__(64) void fc_kernel(
        const float* __restrict__ x, const float* __restrict__ w,
        const float* __restrict__ wb, float* __restrict__ feats) {
    const int row  = blockIdx.x;
    const int lane = threadIdx.x;
    float acc[NT_] = {};
    for (int i = lane; i < H_; i += 64) {
        const float xv = x[(long)row * H_ + i];
        #pragma unroll
        for (int t = 0; t < NT_; ++t) acc[t] += xv * w[i * NT_ + t];
    }
    #pragma unroll
    for (int t = 0; t < NT_; ++t) {
        #pragma unroll
        for (int off = 32; off; off >>= 1) acc[t] += __shfl_down(acc[t], off);
    }
    if (lane == 0) {
        #pragma unroll
        for (int t = 0; t < NT_; ++t) feats[row * NT_ + t] = acc[t] + wb[t];
    }
}

// ---------------------------------------------------------------------------
// Viterbi: single block. Forward 254 steps, then backtrack.
// ---------------------------------------------------------------------------
__global__ __launch_bounds__(128) void viterbi_kernel(
        const float* __restrict__ feats, const float* __restrict__ trans,
        float* __restrict__ out, int* __restrict__ bps) {
    __shared__ float fv[B_][NT_];
    __shared__ float fvn[B_][NT_];
    __shared__ float tr[NT_ * NT_];
    const int tid = threadIdx.x;
    if (tid < NT_ * NT_) tr[tid] = trans[tid];
    if (tid < B_ * NT_) {
        const int b = tid / NT_, i = tid % NT_;
        fv[b][i] = (i == 7) ? 0.0f : NEG_;
    }
    __syncthreads();
    for (int t = 0; t < TLEN_; ++t) {
        if (tid < B_ * NT_) {
            const int b = tid / NT_, i = tid % NT_;
            float best = fv[b][0] + tr[i * NT_ + 0];
            int bj = 0;
            #pragma unroll
            for (int j = 1; j < NT_; ++j) {
                const float c = fv[b][j] + tr[i * NT_ + j];
                if (c > best) { best = c; bj = j; }
            }
            bps[(t * B_ + b) * NT_ + i] = bj;
            fvn[b][i] = best + feats[((b * S_) + 1 + t) * NT_ + i];
        }
        __syncthreads();
        if (tid < B_ * NT_) {
            const int b = tid / NT_, i = tid % NT_;
            fv[b][i] = fvn[b][i];
        }
        __syncthreads();
    }
    if (tid < B_) {
        const int b = tid;
        float best = fv[b][0] + tr[8 * NT_ + 0];
        int bi = 0;
        #pragma unroll
        for (int i = 1; i < NT_; ++i) {
            const float c = fv[b][i] + tr[8 * NT_ + i];
            if (c > best) { best = c; bi = i; }
        }
        out[b] = best;
        float* path = out + B_ + b * TLEN_;
        int tag = bi;
        path[TLEN_ - 1] = (float)tag;
        for (int t = TLEN_ - 2; t >= 0; --t) {
            tag = bps[((t + 1) * B_ + b) * NT_ + tag];
            path[t] = (float)tag;
        }
    }
}

// ---------------------------------------------------------------------------
// Host orchestration
// ---------------------------------------------------------------------------
extern "C" void kernel_launch(void* const* d_in, const int* in_sizes, int n_in,
                              void* d_out, int out_size, void* d_ws, size_t ws_size,
                              hipStream_t stream) {
    const int*   sentences = (const int*)  d_in[0];
    const float* word_emb  = (const float*)d_in[2];
    const float* pos_emb   = (const float*)d_in[3];
    const float* type_emb  = (const float*)d_in[4];
    const float* emb_ln_s  = (const float*)d_in[5];
    const float* emb_ln_b  = (const float*)d_in[6];
    const float* Wq = (const float*)d_in[7];
    const float* bq = (const float*)d_in[8];
    const float* Wk = (const float*)d_in[9];
    const float* bk = (const float*)d_in[10];
    const float* Wv = (const float*)d_in[11];
    const float* bv = (const float*)d_in[12];
    const float* Wo = (const float*)d_in[13];
    const float* bo = (const float*)d_in[14];
    const float* ln1_s = (const float*)d_in[15];
    const float* ln1_b = (const float*)d_in[16];
    const float* W1 = (const float*)d_in[17];
    const float* b1 = (const float*)d_in[18];
    const float* W2 = (const float*)d_in[19];
    const float* b2 = (const float*)d_in[20];
    const float* ln2_s = (const float*)d_in[21];
    const float* ln2_b = (const float*)d_in[22];
    const float* fc_w  = (const float*)d_in[23];
    const float* fc_b  = (const float*)d_in[24];
    const float* transitions = (const float*)d_in[25];

    float* wsf = (float*)d_ws;
    const long NTOKH = (long)TOK_ * H_;        // 1,572,864
    float* x    = wsf;
    float* q    = x + NTOKH;
    float* kbuf = q + NTOKH;
    float* vbuf = kbuf + NTOKH;
    float* ffh  = vbuf + NTOKH;
    float* feats = ffh + (long)TOK_ * FF_;
    int*   bps  = (int*)(feats + (long)TOK_ * NT_);

    embed_ln_kernel<<<TOK_, 256, 0, stream>>>(sentences, word_emb, pos_emb,
                                              type_emb, emb_ln_s, emb_ln_b, x);

    const dim3 gH(H_ / 64, TOK_ / 64);    // 12 x 32 = 384 blocks
    const dim3 gF(FF_ / 64, TOK_ / 64);   // 48 x 32 = 1536 blocks

    for (int l = 0; l < NL_; ++l) {
        const float* Wq_l = Wq + (long)l * H_ * H_;
        const float* Wk_l = Wk + (long)l * H_ * H_;
        const float* Wv_l = Wv + (long)l * H_ * H_;
        const float* Wo_l = Wo + (long)l * H_ * H_;
        const float* W1_l = W1 + (long)l * H_ * FF_;
        const float* W2_l = W2 + (long)l * FF_ * H_;

        mfma_gemm_kernel<0><<<gH, 256, 0, stream>>>(x, Wq_l, bq + l * H_, q,    TOK_, H_, H_);
        mfma_gemm_kernel<0><<<gH, 256, 0, stream>>>(x, Wk_l, bk + l * H_, kbuf, TOK_, H_, H_);
        mfma_gemm_kernel<0><<<gH, 256, 0, stream>>>(x, Wv_l, bv + l * H_, vbuf, TOK_, H_, H_);

        attn_kernel<<<B_ * NH_, 256, 0, stream>>>(q, kbuf, vbuf, q);  // ctx -> q

        mfma_gemm_kernel<0><<<gH, 256, 0, stream>>>(q, Wo_l, bo + l * H_, kbuf, TOK_, H_, H_);
        resid_ln_kernel<<<TOK_, 256, 0, stream>>>(x, kbuf, ln1_s + l * H_, ln1_b + l * H_, x);

        mfma_gemm_kernel<1><<<gF, 256, 0, stream>>>(x, W1_l, b1 + l * FF_, ffh, TOK_, FF_, H_);
        mfma_gemm_kernel<0><<<gH, 256, 0, stream>>>(ffh, W2_l, b2 + l * H_, kbuf, TOK_, H_, FF_);
        resid_ln_kernel<<<TOK_, 256, 0, stream>>>(x, kbuf, ln2_s + l * H_, ln2_b + l * H_, x);
    }

    fc_kernel<<<TOK_, 64, 0, stream>>>(x, fc_w, fc_b, feats);
    viterbi_kernel<<<1, 128, 0, stream>>>(feats, transitions, (float*)d_out, bps);
}

// Round 4
// 5085.671 us; speedup vs baseline: 2.3631x; 1.3958x over previous
//
#include <hip/hip_runtime.h>
#include <math.h>

#define B_ 8
#define S_ 256
#define H_ 768
#define NL_ 12
#define NH_ 12
#define DH_ 64
#define FF_ 3072
#define NT_ 9
#define TLEN_ 254
#define NEG_ -10000.0f
#define TOK_ (B_ * S_)   // 2048

typedef __bf16 bf16x8 __attribute__((ext_vector_type(8)));
typedef float  f32x4  __attribute__((ext_vector_type(4)));

// ---------------------------------------------------------------------------
// bf16 split helpers: f ≈ hi + lo with hi,lo bf16 (RNE). Error ~2^-17 rel.
// ---------------------------------------------------------------------------
__device__ __forceinline__ unsigned short bf16_rne(float f) {
    unsigned int u = __float_as_uint(f);
    unsigned int r = u + 0x7FFFu + ((u >> 16) & 1u);
    return (unsigned short)(r >> 16);
}
__device__ __forceinline__ void split_bf16(float f, unsigned short& h, unsigned short& l) {
    h = bf16_rne(f);
    const float hf = __uint_as_float((unsigned int)h << 16);
    l = bf16_rne(f - hf);
}

// ---------------------------------------------------------------------------
// Block-wide sum+sumsq reduction (256 threads)
// ---------------------------------------------------------------------------
__device__ __forceinline__ void block_reduce2(float& sum, float& ssq) {
    #pragma unroll
    for (int off = 32; off; off >>= 1) {
        sum += __shfl_down(sum, off);
        ssq += __shfl_down(ssq, off);
    }
    __shared__ float rs[4], rq[4];
    const int w = threadIdx.x >> 6;
    if ((threadIdx.x & 63) == 0) { rs[w] = sum; rq[w] = ssq; }
    __syncthreads();
    sum = rs[0] + rs[1] + rs[2] + rs[3];
    ssq = rq[0] + rq[1] + rq[2] + rq[3];
}

// ---------------------------------------------------------------------------
// Embedding gather + LayerNorm  (one block per token)
// ---------------------------------------------------------------------------
__global__ __launch_bounds__(256) void embed_ln_kernel(
        const int* __restrict__ sent, const float* __restrict__ we,
        const float* __restrict__ pe, const float* __restrict__ te,
        const float* __restrict__ g, const float* __restrict__ bb,
        float* __restrict__ out) {
    const int row = blockIdx.x;
    const int s   = row & (S_ - 1);
    const int tid = threadIdx.x;
    const int id  = sent[row];
    float v[3];
    #pragma unroll
    for (int u = 0; u < 3; ++u) {
        const int i = tid + u * 256;
        v[u] = we[(long)id * H_ + i] + pe[s * H_ + i] + te[i];
    }
    float sum = v[0] + v[1] + v[2];
    float ssq = v[0]*v[0] + v[1]*v[1] + v[2]*v[2];
    block_reduce2(sum, ssq);
    const float mean = sum * (1.0f / H_);
    const float var  = ssq * (1.0f / H_) - mean * mean;
    const float inv  = 1.0f / sqrtf(var + 1e-12f);
    #pragma unroll
    for (int u = 0; u < 3; ++u) {
        const int i = tid + u * 256;
        out[row * H_ + i] = (v[u] - mean) * inv * g[i] + bb[i];
    }
}

// ---------------------------------------------------------------------------
// Residual add + LayerNorm
// ---------------------------------------------------------------------------
__global__ __launch_bounds__(256) void resid_ln_kernel(
        const float* __restrict__ x, const float* __restrict__ y,
        const float* __restrict__ g, const float* __restrict__ bb,
        float* __restrict__ out) {
    const int row = blockIdx.x;
    const int tid = threadIdx.x;
    float v[3];
    #pragma unroll
    for (int u = 0; u < 3; ++u) {
        const int i = tid + u * 256;
        v[u] = x[row * H_ + i] + y[row * H_ + i];
    }
    float sum = v[0] + v[1] + v[2];
    float ssq = v[0]*v[0] + v[1]*v[1] + v[2]*v[2];
    block_reduce2(sum, ssq);
    const float mean = sum * (1.0f / H_);
    const float var  = ssq * (1.0f / H_) - mean * mean;
    const float inv  = 1.0f / sqrtf(var + 1e-12f);
    #pragma unroll
    for (int u = 0; u < 3; ++u) {
        const int i = tid + u * 256;
        out[row * H_ + i] = (v[u] - mean) * inv * g[i] + bb[i];
    }
}

// ---------------------------------------------------------------------------
// MFMA bf16 split-precision GEMM: C = A[M,K] @ B[K,N] + bias; EPI==1 -> GELU.
// acc += Ahi*Bhi + Ahi*Blo + Alo*Bhi  (fp32 MFMA accumulate, ~2^-17 rel err).
// Block 64x64, BK=32, 4 waves of 32x32 (2x2 frags of 16x16x32).
// ---------------------------------------------------------------------------
template <int EPI>
__global__ __launch_bounds__(256) void mfma_gemm_kernel(
        const float* __restrict__ A, const float* __restrict__ B,
        const float* __restrict__ bias, float* __restrict__ C,
        int M, int N, int K) {
    __shared__ unsigned short As_hi[64 * 40];
    __shared__ unsigned short As_lo[64 * 40];
    __shared__ unsigned short Bs_hi[64 * 40];
    __shared__ unsigned short Bs_lo[64 * 40];

    const int tid  = threadIdx.x;
    const int lane = tid & 63;
    const int wid  = tid >> 6;
    const int row0 = blockIdx.y * 64;
    const int col0 = blockIdx.x * 64;
    const int wm = (wid >> 1) * 32;
    const int wn = (wid & 1) * 32;
    const int lr = lane & 15;
    const int lk = (lane >> 4) * 8;

    const int ar = tid >> 2, aq = tid & 3;
    const int bn = tid >> 2, bq = tid & 3;

    const float* Ap = A + (long)(row0 + ar) * K + aq * 4;
    const float* Bp = B + (long)(bq * 4) * N + col0 + bn;

    f32x4 acc[2][2];
    #pragma unroll
    for (int mi = 0; mi < 2; ++mi)
        #pragma unroll
        for (int nj = 0; nj < 2; ++nj)
            acc[mi][nj] = (f32x4)(0.0f);

    for (int k0 = 0; k0 < K; k0 += 32) {
        const float4 av0 = *(const float4*)(Ap + k0);
        const float4 av1 = *(const float4*)(Ap + k0 + 16);
        float bvf[8];
        #pragma unroll
        for (int i = 0; i < 4; ++i) bvf[i]     = Bp[(long)(k0 + i) * N];
        #pragma unroll
        for (int i = 0; i < 4; ++i) bvf[4 + i] = Bp[(long)(k0 + 16 + i) * N];

        const float afv[8] = {av0.x, av0.y, av0.z, av0.w, av1.x, av1.y, av1.z, av1.w};
        unsigned short ah8[8], al8[8], bh8[8], bl8[8];
        #pragma unroll
        for (int i = 0; i < 8; ++i) { split_bf16(afv[i], ah8[i], al8[i]); }
        #pragma unroll
        for (int i = 0; i < 8; ++i) { split_bf16(bvf[i], bh8[i], bl8[i]); }

        __syncthreads();

        *(ushort4*)&As_hi[ar * 40 + aq * 4]      = make_ushort4(ah8[0], ah8[1], ah8[2], ah8[3]);
        *(ushort4*)&As_hi[ar * 40 + aq * 4 + 16] = make_ushort4(ah8[4], ah8[5], ah8[6], ah8[7]);
        *(ushort4*)&As_lo[ar * 40 + aq * 4]      = make_ushort4(al8[0], al8[1], al8[2], al8[3]);
        *(ushort4*)&As_lo[ar * 40 + aq * 4 + 16] = make_ushort4(al8[4], al8[5], al8[6], al8[7]);
        *(ushort4*)&Bs_hi[bn * 40 + bq * 4]      = make_ushort4(bh8[0], bh8[1], bh8[2], bh8[3]);
        *(ushort4*)&Bs_hi[bn * 40 + bq * 4 + 16] = make_ushort4(bh8[4], bh8[5], bh8[6], bh8[7]);
        *(ushort4*)&Bs_lo[bn * 40 + bq * 4]      = make_ushort4(bl8[0], bl8[1], bl8[2], bl8[3]);
        *(ushort4*)&Bs_lo[bn * 40 + bq * 4 + 16] = make_ushort4(bl8[4], bl8[5], bl8[6], bl8[7]);

        __syncthreads();

        bf16x8 ah[2], al[2], bh[2], bl[2];
        #pragma unroll
        for (int mi = 0; mi < 2; ++mi) {
            ah[mi] = *(const bf16x8*)&As_hi[(wm + mi * 16 + lr) * 40 + lk];
            al[mi] = *(const bf16x8*)&As_lo[(wm + mi * 16 + lr) * 40 + lk];
        }
        #pragma unroll
        for (int nj = 0; nj < 2; ++nj) {
            bh[nj] = *(const bf16x8*)&Bs_hi[(wn + nj * 16 + lr) * 40 + lk];
            bl[nj] = *(const bf16x8*)&Bs_lo[(wn + nj * 16 + lr) * 40 + lk];
        }
        #pragma unroll
        for (int mi = 0; mi < 2; ++mi)
            #pragma unroll
            for (int nj = 0; nj < 2; ++nj) {
                acc[mi][nj] = __builtin_amdgcn_mfma_f32_16x16x32_bf16(ah[mi], bh[nj], acc[mi][nj], 0, 0, 0);
                acc[mi][nj] = __builtin_amdgcn_mfma_f32_16x16x32_bf16(ah[mi], bl[nj], acc[mi][nj], 0, 0, 0);
                acc[mi][nj] = __builtin_amdgcn_mfma_f32_16x16x32_bf16(al[mi], bh[nj], acc[mi][nj], 0, 0, 0);
            }
    }

    #pragma unroll
    for (int nj = 0; nj < 2; ++nj) {
        const int col = col0 + wn + nj * 16 + lr;
        const float bval = bias[col];
        #pragma unroll
        for (int mi = 0; mi < 2; ++mi) {
            const int rowb = row0 + wm + mi * 16 + (lane >> 4) * 4;
            #pragma unroll
            for (int r = 0; r < 4; ++r) {
                float z = acc[mi][nj][r] + bval;
                if (EPI == 1) z = 0.5f * z * (1.0f + erff(z * 0.70710678118654752f));
                C[(long)(rowb + r) * N + col] = z;
            }
        }
    }
}

// ---------------------------------------------------------------------------
// Fused attention v2: block = (b, head, q-tile of 64). 256 threads =
// 64 queries x 4 lanes; each lane owns 16 of the 64 dims. QK^T partials
// reduced across the 4-lane group via shfl_xor; softmax state replicated.
// O aliases Q safely (disjoint (row, col-range) per block/thread).
// ---------------------------------------------------------------------------
__global__ __launch_bounds__(256) void attn_kernel(
        const float* __restrict__ Q, const float* __restrict__ K,
        const float* __restrict__ V, float* __restrict__ O) {
    const int blk = blockIdx.x;
    const int qt  = blk & 3;
    const int bh  = blk >> 2;
    const int b   = bh / NH_;
    const int h   = bh % NH_;
    const int tid = threadIdx.x;
    const int ql  = tid >> 2;            // local query 0..63
    const int d0  = (tid & 3) * 16;      // owned d-range
    __shared__ float Ks[64][68];
    __shared__ float Vs[64][68];
    const long base = (long)(b * S_) * H_ + h * DH_;
    const int qrow = qt * 64 + ql;

    float qr[16];
    #pragma unroll
    for (int d4 = 0; d4 < 4; ++d4) {
        const float4 t = *(const float4*)&Q[base + (long)qrow * H_ + d0 + d4 * 4];
        qr[d4*4+0] = t.x * 0.125f; qr[d4*4+1] = t.y * 0.125f;
        qr[d4*4+2] = t.z * 0.125f; qr[d4*4+3] = t.w * 0.125f;
    }
    float acc[16] = {};
    float m_run = -1e30f, l_run = 0.0f;

    for (int kt = 0; kt < 4; ++kt) {
        __syncthreads();
        #pragma unroll
        for (int u = 0; u < 4; ++u) {
            const int idx = tid + u * 256;
            const int r = idx >> 4, c = (idx & 15) * 4;
            *(float4*)&Ks[r][c] = *(const float4*)&K[base + (long)(kt*64 + r) * H_ + c];
            *(float4*)&Vs[r][c] = *(const float4*)&V[base + (long)(kt*64 + r) * H_ + c];
        }
        __syncthreads();
        for (int ch = 0; ch < 4; ++ch) {
            float sreg[16];
            float mx = -1e30f;
            #pragma unroll
            for (int jj = 0; jj < 16; ++jj) {
                const int j = ch * 16 + jj;
                float a = 0.0f;
                #pragma unroll
                for (int d4 = 0; d4 < 4; ++d4) {
                    const float4 kv = *(const float4*)&Ks[j][d0 + d4 * 4];
                    a += qr[d4*4+0]*kv.x + qr[d4*4+1]*kv.y
                       + qr[d4*4+2]*kv.z + qr[d4*4+3]*kv.w;
                }
                a += __shfl_xor(a, 1);
                a += __shfl_xor(a, 2);
                sreg[jj] = a;
                mx = fmaxf(mx, a);
            }
            const float m_new = fmaxf(m_run, mx);
            const float corr  = __expf(m_run - m_new);
            l_run *= corr;
            #pragma unroll
            for (int d = 0; d < 16; ++d) acc[d] *= corr;
            #pragma unroll
            for (int jj = 0; jj < 16; ++jj) {
                const float p = __expf(sreg[jj] - m_new);
                l_run += p;
                const int j = ch * 16 + jj;
                #pragma unroll
                for (int d4 = 0; d4 < 4; ++d4) {
                    const float4 vv = *(const float4*)&Vs[j][d0 + d4 * 4];
                    acc[d4*4+0] += p * vv.x; acc[d4*4+1] += p * vv.y;
                    acc[d4*4+2] += p * vv.z; acc[d4*4+3] += p * vv.w;
                }
            }
            m_run = m_new;
        }
    }
    const float inv = 1.0f / l_run;
    #pragma unroll
    for (int d4 = 0; d4 < 4; ++d4) {
        float o[4];
        o[0] = acc[d4*4+0] * inv; o[1] = acc[d4*4+1] * inv;
        o[2] = acc[d4*4+2] * inv; o[3] = acc[d4*4+3] * inv;
        *(float4*)&O[base + (long)qrow * H_ + d0 + d4 * 4] = *(float4*)o;
    }
}

// ---------------------------------------------------------------------------
// Final FC: feats[row, 0..8] = x[row,:] @ fc_w + fc_b  (one wave per row)
// ---------------------------------------------------------------------------
__global__ __launch_bounds__(64) void fc_kernel(
        const float* __restrict__ x, const float* __restrict__ w,
        const float* __restrict__ wb, float* __restrict__ feats) {
    const int row  = blockIdx.x;
    const int lane = threadIdx.x;
    float acc[NT_] = {};
    for (int i = lane; i < H_; i += 64) {
        const float xv = x[(long)row * H_ + i];
        #pragma unroll
        for (int t = 0; t < NT_; ++t) acc[t] += xv * w[i * NT_ + t];
    }
    #pragma unroll
    for (int t = 0; t < NT_; ++t) {
        #pragma unroll
        for (int off = 32; off; off >>= 1) acc[t] += __shfl_down(acc[t], off);
    }
    if (lane == 0) {
        #pragma unroll
        for (int t = 0; t < NT_; ++t) feats[row * NT_ + t] = acc[t] + wb[t];
    }
}

// ---------------------------------------------------------------------------
// Viterbi: single block. Forward 254 steps, then backtrack.
// ---------------------------------------------------------------------------
__global__ __launch_bounds__(128) void viterbi_kernel(
        const float* __restrict__ feats, const float* __restrict__ trans,
        float* __restrict__ out, int* __restrict__ bps) {
    __shared__ float fv[B_][NT_];
    __shared__ float fvn[B_][NT_];
    __shared__ float tr[NT_ * NT_];
    const int tid = threadIdx.x;
    if (tid < NT_ * NT_) tr[tid] = trans[tid];
    if (tid < B_ * NT_) {
        const int b = tid / NT_, i = tid % NT_;
        fv[b][i] = (i == 7) ? 0.0f : NEG_;
    }
    __syncthreads();
    for (int t = 0; t < TLEN_; ++t) {
        if (tid < B_ * NT_) {
            const int b = tid / NT_, i = tid % NT_;
            float best = fv[b][0] + tr[i * NT_ + 0];
            int bj = 0;
            #pragma unroll
            for (int j = 1; j < NT_; ++j) {
                const float c = fv[b][j] + tr[i * NT_ + j];
                if (c > best) { best = c; bj = j; }
            }
            bps[(t * B_ + b) * NT_ + i] = bj;
            fvn[b][i] = best + feats[((b * S_) + 1 + t) * NT_ + i];
        }
        __syncthreads();
        if (tid < B_ * NT_) {
            const int b = tid / NT_, i = tid % NT_;
            fv[b][i] = fvn[b][i];
        }
        __syncthreads();
    }
    if (tid < B_) {
        const int b = tid;
        float best = fv[b][0] + tr[8 * NT_ + 0];
        int bi = 0;
        #pragma unroll
        for (int i = 1; i < NT_; ++i) {
            const float c = fv[b][i] + tr[8 * NT_ + i];
            if (c > best) { best = c; bi = i; }
        }
        out[b] = best;
        float* path = out + B_ + b * TLEN_;
        int tag = bi;
        path[TLEN_ - 1] = (float)tag;
        for (int t = TLEN_ - 2; t >= 0; --t) {
            tag = bps[((t + 1) * B_ + b) * NT_ + tag];
            path[t] = (float)tag;
        }
    }
}

// ---------------------------------------------------------------------------
// Host orchestration
// ---------------------------------------------------------------------------
extern "C" void kernel_launch(void* const* d_in, const int* in_sizes, int n_in,
                              void* d_out, int out_size, void* d_ws, size_t ws_size,
                              hipStream_t stream) {
    const int*   sentences = (const int*)  d_in[0];
    const float* word_emb  = (const float*)d_in[2];
    const float* pos_emb   = (const float*)d_in[3];
    const float* type_emb  = (const float*)d_in[4];
    const float* emb_ln_s  = (const float*)d_in[5];
    const float* emb_ln_b  = (const float*)d_in[6];
    const float* Wq = (const float*)d_in[7];
    const float* bq = (const float*)d_in[8];
    const float* Wk = (const float*)d_in[9];
    const float* bk = (const float*)d_in[10];
    const float* Wv = (const float*)d_in[11];
    const float* bv = (const float*)d_in[12];
    const float* Wo = (const float*)d_in[13];
    const float* bo = (const float*)d_in[14];
    const float* ln1_s = (const float*)d_in[15];
    const float* ln1_b = (const float*)d_in[16];
    const float* W1 = (const float*)d_in[17];
    const float* b1 = (const float*)d_in[18];
    const float* W2 = (const float*)d_in[19];
    const float* b2 = (const float*)d_in[20];
    const float* ln2_s = (const float*)d_in[21];
    const float* ln2_b = (const float*)d_in[22];
    const float* fc_w  = (const float*)d_in[23];
    const float* fc_b  = (const float*)d_in[24];
    const float* transitions = (const float*)d_in[25];

    float* wsf = (float*)d_ws;
    const long NTOKH = (long)TOK_ * H_;
    float* x    = wsf;
    float* q    = x + NTOKH;
    float* kbuf = q + NTOKH;
    float* vbuf = kbuf + NTOKH;
    float* ffh  = vbuf + NTOKH;
    float* feats = ffh + (long)TOK_ * FF_;
    int*   bps  = (int*)(feats + (long)TOK_ * NT_);

    embed_ln_kernel<<<TOK_, 256, 0, stream>>>(sentences, word_emb, pos_emb,
                                              type_emb, emb_ln_s, emb_ln_b, x);

    const dim3 gH(H_ / 64, TOK_ / 64);    // 12 x 32 = 384 blocks
    const dim3 gF(FF_ / 64, TOK_ / 64);   // 48 x 32 = 1536 blocks

    for (int l = 0; l < NL_; ++l) {
        const float* Wq_l = Wq + (long)l * H_ * H_;
        const float* Wk_l = Wk + (long)l * H_ * H_;
        const float* Wv_l = Wv + (long)l * H_ * H_;
        const float* Wo_l = Wo + (long)l * H_ * H_;
        const float* W1_l = W1 + (long)l * H_ * FF_;
        const float* W2_l = W2 + (long)l * FF_ * H_;

        mfma_gemm_kernel<0><<<gH, 256, 0, stream>>>(x, Wq_l, bq + l * H_, q,    TOK_, H_, H_);
        mfma_gemm_kernel<0><<<gH, 256, 0, stream>>>(x, Wk_l, bk + l * H_, kbuf, TOK_, H_, H_);
        mfma_gemm_kernel<0><<<gH, 256, 0, stream>>>(x, Wv_l, bv + l * H_, vbuf, TOK_, H_, H_);

        attn_kernel<<<B_ * NH_ * 4, 256, 0, stream>>>(q, kbuf, vbuf, q);  // ctx -> q

        mfma_gemm_kernel<0><<<gH, 256, 0, stream>>>(q, Wo_l, bo + l * H_, kbuf, TOK_, H_, H_);
        resid_ln_kernel<<<TOK_, 256, 0, stream>>>(x, kbuf, ln1_s + l * H_, ln1_b + l * H_, x);

        mfma_gemm_kernel<1><<<gF, 256, 0, stream>>>(x, W1_l, b1 + l * FF_, ffh, TOK_, FF_, H_);
        mfma_gemm_kernel<0><<<gH, 256, 0, stream>>>(ffh, W2_l, b2 + l * H_, kbuf, TOK_, H_, FF_);
        resid_ln_kernel<<<TOK_, 256, 0, stream>>>(x, kbuf, ln2_s + l * H_, ln2_b + l * H_, x);
    }

    fc_kernel<<<TOK_, 64, 0, stream>>>(x, fc_w, fc_b, feats);
    viterbi_kernel<<<1, 128, 0, stream>>>(feats, transitions, (float*)d_out, bps);
}